// Round 2
// baseline (386.400 us; speedup 1.0000x reference)
//
#include <hip/hip_runtime.h>
#include <math.h>

typedef unsigned short ushort_t;
typedef __attribute__((ext_vector_type(8))) short bf16x8;
typedef __attribute__((ext_vector_type(4))) float f32x4;
typedef __attribute__((ext_vector_type(8))) unsigned short u16x8;

#define N_TOK 65536
#define DIN 128
#define HD 256
#define DOUT 128
#define NEXP 8
#define MT 64
#define MAX_TILES (N_TOK / MT) /* 1024 */

__device__ __forceinline__ unsigned short f2bf(float f) {
    union { float f; unsigned int i; } v; v.f = f;
    unsigned int i = v.i;
    return (unsigned short)((i + 0x7FFFu + ((i >> 16) & 1u)) >> 16); // RNE
}

// ---------------------------------------------------------------------------
// Pack fp32 W1/W2/Wo into bf16 MFMA B-fragment order:
// chunk index (per expert) = (ntile*KSTEPS + kstep)*64 + lane, lane=q*16+m,
// chunk content j=0..7 = W[k = kstep*32 + q*8 + j][n = ntile*16 + m].
// W1: 8 x (16 ntiles * 4 ksteps * 64) = 32768 chunks
// W2: 8 x (16 * 8 * 64)              = 65536 chunks
// Wo: (8 * 8 * 64)                   =  4096 chunks   -> 102400 total
// ---------------------------------------------------------------------------
__global__ void pack_weights(const float* __restrict__ W1,
                             const float* __restrict__ W2,
                             const float* __restrict__ Wo,
                             ushort_t* __restrict__ wt1f,
                             ushort_t* __restrict__ wt2f,
                             ushort_t* __restrict__ wotf) {
    int id = blockIdx.x * 256 + threadIdx.x;
    const float* src; ushort_t* dst; int Nn, ksteps, c;
    if (id < 32768) {            // W1
        int e = id >> 12; c = id & 4095;
        Nn = HD; ksteps = 4; src = W1 + (size_t)e * DIN * HD; dst = wt1f + (size_t)id * 8;
    } else if (id < 98304) {     // W2
        int t = id - 32768; int e = t >> 13; c = t & 8191;
        Nn = HD; ksteps = 8; src = W2 + (size_t)e * HD * HD; dst = wt2f + (size_t)t * 8;
    } else {                     // Wo
        int t = id - 98304; c = t;
        Nn = DOUT; ksteps = 8; src = Wo; dst = wotf + (size_t)t * 8;
    }
    int L = c & 63; int kc = c >> 6;
    int kstep = kc % ksteps; int ntile = kc / ksteps;
    int q = L >> 4, m = L & 15;
    int n = ntile * 16 + m; int k0 = kstep * 32 + q * 8;
    u16x8 v;
#pragma unroll
    for (int j = 0; j < 8; j++) v[j] = f2bf(src[(size_t)(k0 + j) * Nn + n]);
    *(u16x8*)dst = v;
}

// ---------------------------------------------------------------------------
// Router: logits = x @ Wg (fp32), top-2, softmax over the 2, ballot-
// aggregated list insert. Entry = token index; weight in list_w.
// ---------------------------------------------------------------------------
__global__ void router_kernel(const float* __restrict__ x,
                              const float* __restrict__ Wg,
                              int* __restrict__ counts,
                              int* __restrict__ list_tok,
                              float* __restrict__ list_w) {
    __shared__ float wgs[DIN * NEXP];
    int tid = threadIdx.x;
    for (int i = tid; i < DIN * NEXP; i += 256) wgs[i] = Wg[i];
    __syncthreads();

    int n = blockIdx.x * 256 + tid;
    const float4* xr = (const float4*)(x + (size_t)n * DIN);
    float lg[NEXP];
#pragma unroll
    for (int e = 0; e < NEXP; e++) lg[e] = 0.f;
#pragma unroll 8
    for (int c = 0; c < 32; c++) {
        float4 p = xr[c];
        int k = c * 4;
#pragma unroll
        for (int e = 0; e < NEXP; e++) {
            lg[e] += p.x * wgs[(k + 0) * NEXP + e];
            lg[e] += p.y * wgs[(k + 1) * NEXP + e];
            lg[e] += p.z * wgs[(k + 2) * NEXP + e];
            lg[e] += p.w * wgs[(k + 3) * NEXP + e];
        }
    }
    // top-2 (ties -> lowest index, matching lax.top_k)
    int e0 = 0; float v0 = lg[0];
#pragma unroll
    for (int e = 1; e < NEXP; e++) if (lg[e] > v0) { v0 = lg[e]; e0 = e; }
    int e1 = -1; float v1 = -1e30f;
#pragma unroll
    for (int e = 0; e < NEXP; e++) if (e != e0 && lg[e] > v1) { v1 = lg[e]; e1 = e; }
    float t = expf(v1 - v0);
    float inv = 1.0f / (1.0f + t);
    float w0 = inv, w1 = t * inv;

    int lane = tid & 63;
#pragma unroll
    for (int s = 0; s < 2; s++) {
        int es = (s == 0) ? e0 : e1;
        float wsv = (s == 0) ? w0 : w1;
        for (int ex = 0; ex < NEXP; ex++) {
            unsigned long long mask = __ballot(es == ex);
            if (mask) {
                int leader = __ffsll(mask) - 1;
                int tot = __popcll(mask);
                int basep = 0;
                if (lane == leader) basep = atomicAdd(&counts[ex], tot);
                basep = __shfl(basep, leader, 64);
                if (es == ex) {
                    int prior = __popcll(mask & ((1ull << lane) - 1ull));
                    int p = basep + prior;
                    list_tok[ex * N_TOK + p] = n;
                    list_w[ex * N_TOK + p] = wsv;
                }
            }
        }
    }
}

// ---------------------------------------------------------------------------
// init d_out with broadcast bo (softmax weights sum to 1, bo added once).
// ---------------------------------------------------------------------------
__global__ void init_out(const float* __restrict__ bo, float* __restrict__ out) {
    int gid = blockIdx.x * 256 + threadIdx.x; // N*DOUT/4 float4 groups
    float4 b = ((const float4*)bo)[gid & 31];
    ((float4*)out)[gid] = b;
}

// ---------------------------------------------------------------------------
// Fused per-expert MLP over 64-token tiles (bf16 MFMA, fp32 accumulate).
// LDS A-fragment layout: chunk = (kstep*4 + mtile)*64 + (q*16 + m), 8 bf16/chunk.
// B-fragments loaded straight from packed global (L2-hot).
// Epilogue: atomicAdd of w * y into d_out (2 adds per (token,col) total).
// ---------------------------------------------------------------------------
__global__ __launch_bounds__(256, 2)
void expert_kernel(const float* __restrict__ x,
                   const int* __restrict__ counts,
                   const int* __restrict__ list_tok,
                   const float* __restrict__ list_w,
                   const ushort_t* __restrict__ wt1f,
                   const ushort_t* __restrict__ wt2f,
                   const ushort_t* __restrict__ wotf,
                   const float* __restrict__ b1,
                   const float* __restrict__ b2,
                   float* __restrict__ out) {
    int e = blockIdx.x & 7;
    int tile = blockIdx.x >> 3;
    int cnt = counts[e];
    int base = tile * MT;
    if (base >= cnt) return;
    int rows = cnt - base; if (rows > MT) rows = MT;

    __shared__ __align__(16) ushort_t bufA[16384]; // 32KB: x (first 16KB), later h2
    __shared__ __align__(16) ushort_t bufH[16384]; // 32KB: h1
    __shared__ int toks_s[MT];
    __shared__ float wts_s[MT];

    int tid = threadIdx.x;
    int lane = tid & 63;
    int w = tid >> 6;
    int q = lane >> 4;
    int mcol = lane & 15;

    if (tid < MT) {
        int rr = tid < rows ? tid : rows - 1;
        toks_s[tid] = list_tok[(size_t)e * N_TOK + base + rr];
        wts_s[tid] = list_w[(size_t)e * N_TOK + base + rr];
    }
    // stage x tile (fp32 -> bf16) into A-frag layout (1024 16B chunks)
    for (int c = tid; c < 1024; c += 256) {
        int row = c >> 4;
        int kchunk = c & 15;
        int rr = row < rows ? row : rows - 1;
        int tok = list_tok[(size_t)e * N_TOK + base + rr];
        const float4* src = (const float4*)(x + (size_t)tok * DIN + kchunk * 8);
        float4 lo = src[0], hi = src[1];
        u16x8 v;
        v[0] = f2bf(lo.x); v[1] = f2bf(lo.y); v[2] = f2bf(lo.z); v[3] = f2bf(lo.w);
        v[4] = f2bf(hi.x); v[5] = f2bf(hi.y); v[6] = f2bf(hi.z); v[7] = f2bf(hi.w);
        int kstep = kchunk >> 2, qq = kchunk & 3;
        int dchunk = (kstep * 4 + (row >> 4)) * 64 + qq * 16 + (row & 15);
        ((u16x8*)bufA)[dchunk] = v;
    }
    __syncthreads();

    const bf16x8* Albs = (const bf16x8*)bufA;
    const bf16x8* Hlbs = (const bf16x8*)bufH;

    // ---- GEMM1: x[64x128] @ W1[128x256] -> h1 ----
    f32x4 acc[4][4];
#pragma unroll
    for (int mt = 0; mt < 4; mt++)
#pragma unroll
        for (int nt = 0; nt < 4; nt++) acc[mt][nt] = (f32x4){0.f, 0.f, 0.f, 0.f};
    const bf16x8* B1 = (const bf16x8*)(wt1f + (size_t)e * 4096 * 8);
#pragma unroll
    for (int kstep = 0; kstep < 4; kstep++) {
        bf16x8 a[4];
#pragma unroll
        for (int mt = 0; mt < 4; mt++) a[mt] = Albs[(kstep * 4 + mt) * 64 + lane];
#pragma unroll
        for (int nt = 0; nt < 4; nt++) {
            bf16x8 b = B1[((w * 4 + nt) * 4 + kstep) * 64 + lane];
#pragma unroll
            for (int mt = 0; mt < 4; mt++)
                acc[mt][nt] = __builtin_amdgcn_mfma_f32_16x16x32_bf16(a[mt], b, acc[mt][nt], 0, 0, 0);
        }
    }
    // epilogue 1: bias + relu -> bufH in A-frag layout
#pragma unroll
    for (int nt = 0; nt < 4; nt++) {
        int nn = (w * 4 + nt) * 16 + mcol;
        float bias = b1[e * HD + nn];
        int kstep = nn >> 5, qq = (nn >> 3) & 3, jj = nn & 7;
#pragma unroll
        for (int mt = 0; mt < 4; mt++) {
#pragma unroll
            for (int r = 0; r < 4; r++) {
                float v = acc[mt][nt][r] + bias;
                v = v > 0.f ? v : 0.f;
                int chunk = (kstep * 4 + mt) * 64 + qq * 16 + q * 4 + r;
                bufH[chunk * 8 + jj] = f2bf(v);
            }
        }
    }
    __syncthreads();

    // ---- GEMM2: h1[64x256] @ W2[256x256] -> h2 (into bufA) ----
    f32x4 acc2[4][4];
#pragma unroll
    for (int mt = 0; mt < 4; mt++)
#pragma unroll
        for (int nt = 0; nt < 4; nt++) acc2[mt][nt] = (f32x4){0.f, 0.f, 0.f, 0.f};
    const bf16x8* B2 = (const bf16x8*)(wt2f + (size_t)e * 8192 * 8);
#pragma unroll
    for (int kstep = 0; kstep < 8; kstep++) {
        bf16x8 a[4];
#pragma unroll
        for (int mt = 0; mt < 4; mt++) a[mt] = Hlbs[(kstep * 4 + mt) * 64 + lane];
#pragma unroll
        for (int nt = 0; nt < 4; nt++) {
            bf16x8 b = B2[((w * 4 + nt) * 8 + kstep) * 64 + lane];
#pragma unroll
            for (int mt = 0; mt < 4; mt++)
                acc2[mt][nt] = __builtin_amdgcn_mfma_f32_16x16x32_bf16(a[mt], b, acc2[mt][nt], 0, 0, 0);
        }
    }
    // epilogue 2: bias + relu -> bufA (h2); bufA's x-data is dead after GEMM1
#pragma unroll
    for (int nt = 0; nt < 4; nt++) {
        int nn = (w * 4 + nt) * 16 + mcol;
        float bias = b2[e * HD + nn];
        int kstep = nn >> 5, qq = (nn >> 3) & 3, jj = nn & 7;
#pragma unroll
        for (int mt = 0; mt < 4; mt++) {
#pragma unroll
            for (int r = 0; r < 4; r++) {
                float v = acc2[mt][nt][r] + bias;
                v = v > 0.f ? v : 0.f;
                int chunk = (kstep * 4 + mt) * 64 + qq * 16 + q * 4 + r;
                bufA[chunk * 8 + jj] = f2bf(v);
            }
        }
    }
    __syncthreads();

    // ---- GEMM3: h2[64x256] @ Wo[256x128] -> y; weighted atomic combine ----
    f32x4 acc3[4][2];
#pragma unroll
    for (int mt = 0; mt < 4; mt++)
#pragma unroll
        for (int nt = 0; nt < 2; nt++) acc3[mt][nt] = (f32x4){0.f, 0.f, 0.f, 0.f};
    const bf16x8* B3 = (const bf16x8*)wotf;
#pragma unroll
    for (int kstep = 0; kstep < 8; kstep++) {
        bf16x8 a[4];
#pragma unroll
        for (int mt = 0; mt < 4; mt++) a[mt] = Albs[(kstep * 4 + mt) * 64 + lane];
#pragma unroll
        for (int nt = 0; nt < 2; nt++) {
            bf16x8 b = B3[((w * 2 + nt) * 8 + kstep) * 64 + lane];
#pragma unroll
            for (int mt = 0; mt < 4; mt++)
                acc3[mt][nt] = __builtin_amdgcn_mfma_f32_16x16x32_bf16(a[mt], b, acc3[mt][nt], 0, 0, 0);
        }
    }
#pragma unroll
    for (int mt = 0; mt < 4; mt++) {
#pragma unroll
        for (int r = 0; r < 4; r++) {
            int row = mt * 16 + q * 4 + r;
            if (row < rows) {
                int tok = toks_s[row];
                float wgt = wts_s[row];
                float* dst = out + (size_t)tok * DOUT;
#pragma unroll
                for (int nt = 0; nt < 2; nt++) {
                    int col = (w * 2 + nt) * 16 + mcol;
                    atomicAdd(&dst[col], wgt * acc3[mt][nt][r]);
                }
            }
        }
    }
}

extern "C" void kernel_launch(void* const* d_in, const int* in_sizes, int n_in,
                              void* d_out, int out_size, void* d_ws, size_t ws_size,
                              hipStream_t stream) {
    const float* x  = (const float*)d_in[0];
    const float* Wg = (const float*)d_in[1];
    const float* W1 = (const float*)d_in[2];
    const float* b1 = (const float*)d_in[3];
    const float* W2 = (const float*)d_in[4];
    const float* b2 = (const float*)d_in[5];
    const float* Wo = (const float*)d_in[6];
    const float* bo = (const float*)d_in[7];
    float* out = (float*)d_out;

    char* ws = (char*)d_ws;
    size_t off = 0;
    int* counts    = (int*)(ws + off);    off += 256;
    int* list_tok  = (int*)(ws + off);    off += (size_t)NEXP * N_TOK * 4;
    float* list_w  = (float*)(ws + off);  off += (size_t)NEXP * N_TOK * 4;
    ushort_t* wt1f = (ushort_t*)(ws + off); off += (size_t)NEXP * DIN * HD * 2;
    ushort_t* wt2f = (ushort_t*)(ws + off); off += (size_t)NEXP * HD * HD * 2;
    ushort_t* wotf = (ushort_t*)(ws + off); off += (size_t)HD * DOUT * 2;

    hipMemsetAsync(counts, 0, 256, stream);
    pack_weights<<<400, 256, 0, stream>>>(W1, W2, Wo, wt1f, wt2f, wotf);
    router_kernel<<<N_TOK / 256, 256, 0, stream>>>(x, Wg, counts, list_tok, list_w);
    init_out<<<(N_TOK * DOUT / 4) / 256, 256, 0, stream>>>(bo, out);
    expert_kernel<<<NEXP * MAX_TILES, 256, 0, stream>>>(x, counts, list_tok, list_w,
                                                        wt1f, wt2f, wotf, b1, b2, out);
}

// Round 3
// 199.640 us; speedup vs baseline: 1.9355x; 1.9355x over previous
//
#include <hip/hip_runtime.h>
#include <math.h>

typedef unsigned short ushort_t;
typedef __attribute__((ext_vector_type(8))) short bf16x8;
typedef __attribute__((ext_vector_type(4))) float f32x4;
typedef __attribute__((ext_vector_type(8))) unsigned short u16x8;

#define N_TOK 65536
#define DIN 128
#define HD 256
#define DOUT 128
#define NEXP 8
#define MT 64
#define MAX_TILES (N_TOK / MT) /* 1024 */

__device__ __forceinline__ unsigned short f2bf(float f) {
    union { float f; unsigned int i; } v; v.f = f;
    unsigned int i = v.i;
    return (unsigned short)((i + 0x7FFFu + ((i >> 16) & 1u)) >> 16); // RNE
}

// ---------------------------------------------------------------------------
// Pack fp32 W1/W2/Wo into bf16 MFMA B-fragment order:
// chunk index (per expert) = (ntile*KSTEPS + kstep)*64 + lane, lane=q*16+m,
// chunk content j=0..7 = W[k = kstep*32 + q*8 + j][n = ntile*16 + m].
// ---------------------------------------------------------------------------
__global__ void pack_weights(const float* __restrict__ W1,
                             const float* __restrict__ W2,
                             const float* __restrict__ Wo,
                             ushort_t* __restrict__ wt1f,
                             ushort_t* __restrict__ wt2f,
                             ushort_t* __restrict__ wotf) {
    int id = blockIdx.x * 256 + threadIdx.x;
    const float* src; ushort_t* dst; int Nn, ksteps, c;
    if (id < 32768) {            // W1
        int e = id >> 12; c = id & 4095;
        Nn = HD; ksteps = 4; src = W1 + (size_t)e * DIN * HD; dst = wt1f + (size_t)id * 8;
    } else if (id < 98304) {     // W2
        int t = id - 32768; int e = t >> 13; c = t & 8191;
        Nn = HD; ksteps = 8; src = W2 + (size_t)e * HD * HD; dst = wt2f + (size_t)t * 8;
    } else {                     // Wo
        int t = id - 98304; c = t;
        Nn = DOUT; ksteps = 8; src = Wo; dst = wotf + (size_t)t * 8;
    }
    int L = c & 63; int kc = c >> 6;
    int kstep = kc % ksteps; int ntile = kc / ksteps;
    int q = L >> 4, m = L & 15;
    int n = ntile * 16 + m; int k0 = kstep * 32 + q * 8;
    u16x8 v;
#pragma unroll
    for (int j = 0; j < 8; j++) v[j] = f2bf(src[(size_t)(k0 + j) * Nn + n]);
    *(u16x8*)dst = v;
}

// ---------------------------------------------------------------------------
// Router, expert-split: 8 lanes per token, lane e computes the full logit
// for expert e (128 FMAs). x loads are lane-broadcast (same addr across the
// 8 lanes of a token, 4KB span per wave -> L1-resident). Wg transposed+padded
// in LDS for conflict-free ds_read_b128. Top-2 via shfl_xor over the 8-lane
// group; list insertion via block-level two-phase counting (LDS atomics for
// local slots, 8 global atomics per block).
// ---------------------------------------------------------------------------
#define RT_BLOCK 512
#define RT_TPB 64   /* tokens per block */
__global__ __launch_bounds__(RT_BLOCK)
void router_kernel(const float* __restrict__ x,
                   const float* __restrict__ Wg,
                   int* __restrict__ counts,
                   int* __restrict__ list_tok,
                   float* __restrict__ list_w) {
    __shared__ float wgsT[NEXP * 132]; // padded leading dim: conflict-free b128
    __shared__ int lcnt[NEXP];
    __shared__ int lbase[NEXP];
    int tid = threadIdx.x;
    if (tid < NEXP) lcnt[tid] = 0;
    for (int i = tid; i < DIN * NEXP; i += RT_BLOCK) {
        int e = i & 7, k = i >> 3;   // Wg[k][e]
        wgsT[e * 132 + k] = Wg[i];
    }
    __syncthreads();

    int e = tid & 7;
    int tl = tid >> 3;
    int n = blockIdx.x * RT_TPB + tl;
    const float4* xr = (const float4*)(x + (size_t)n * DIN);
    const float4* wv4 = (const float4*)(wgsT + e * 132);
    float lg = 0.f;
#pragma unroll
    for (int kk = 0; kk < 32; kk++) {
        float4 xv = xr[kk];
        float4 wv = wv4[kk];
        lg += xv.x * wv.x;
        lg += xv.y * wv.y;
        lg += xv.z * wv.z;
        lg += xv.w * wv.w;
    }
    // top-1 over the 8 lanes of this token (ties -> lowest expert index)
    float v0 = lg; int e0 = e;
#pragma unroll
    for (int d = 1; d < 8; d <<= 1) {
        float ov = __shfl_xor(v0, d, 64);
        int oe = __shfl_xor(e0, d, 64);
        if (ov > v0 || (ov == v0 && oe < e0)) { v0 = ov; e0 = oe; }
    }
    // top-2: mask out e0, reduce again
    float mv = (e == e0) ? -3.0e38f : lg;
    float v1 = mv; int e1 = e;
#pragma unroll
    for (int d = 1; d < 8; d <<= 1) {
        float ov = __shfl_xor(v1, d, 64);
        int oe = __shfl_xor(e1, d, 64);
        if (ov > v1 || (ov == v1 && oe < e1)) { v1 = ov; e1 = oe; }
    }
    float t = expf(v1 - v0);
    float inv = 1.0f / (1.0f + t);
    float w0 = inv, w1 = t * inv;

    bool writer = (e == 0);
    int p0 = 0, p1 = 0;
    if (writer) {
        p0 = atomicAdd(&lcnt[e0], 1);
        p1 = atomicAdd(&lcnt[e1], 1);
    }
    __syncthreads();
    if (tid < NEXP) lbase[tid] = atomicAdd(&counts[tid], lcnt[tid]);
    __syncthreads();
    if (writer) {
        int q0 = lbase[e0] + p0;
        list_tok[e0 * N_TOK + q0] = n;
        list_w[e0 * N_TOK + q0] = w0;
        int q1 = lbase[e1] + p1;
        list_tok[e1 * N_TOK + q1] = n;
        list_w[e1 * N_TOK + q1] = w1;
    }
}

// ---------------------------------------------------------------------------
// init d_out with broadcast bo (softmax weights sum to 1, bo added once).
// ---------------------------------------------------------------------------
__global__ void init_out(const float* __restrict__ bo, float* __restrict__ out) {
    int gid = blockIdx.x * 256 + threadIdx.x; // N*DOUT/4 float4 groups
    float4 b = ((const float4*)bo)[gid & 31];
    ((float4*)out)[gid] = b;
}

// ---------------------------------------------------------------------------
// Fused per-expert MLP over 64-token tiles (bf16 MFMA, fp32 accumulate).
// LDS A-fragment layout: chunk = (kstep*4 + mtile)*64 + (q*16 + m), 8 bf16/chunk.
// B-fragments loaded straight from packed global (L2-hot).
// LDS: bufA 16KB (x tile), bufH 32KB (h1, then h2 in-place after a barrier)
// -> 48.5KB total, 3 blocks/CU.
// ---------------------------------------------------------------------------
__global__ __launch_bounds__(256, 3)
void expert_kernel(const float* __restrict__ x,
                   const int* __restrict__ counts,
                   const int* __restrict__ list_tok,
                   const float* __restrict__ list_w,
                   const ushort_t* __restrict__ wt1f,
                   const ushort_t* __restrict__ wt2f,
                   const ushort_t* __restrict__ wotf,
                   const float* __restrict__ b1,
                   const float* __restrict__ b2,
                   float* __restrict__ out) {
    int e = blockIdx.x & 7;
    int tile = blockIdx.x >> 3;
    int cnt = counts[e];
    int base = tile * MT;
    if (base >= cnt) return;
    int rows = cnt - base; if (rows > MT) rows = MT;

    __shared__ __align__(16) ushort_t bufA[8192];  // 16KB: x tile
    __shared__ __align__(16) ushort_t bufH[16384]; // 32KB: h1, then h2
    __shared__ int toks_s[MT];
    __shared__ float wts_s[MT];

    int tid = threadIdx.x;
    int lane = tid & 63;
    int w = tid >> 6;
    int q = lane >> 4;
    int mcol = lane & 15;

    if (tid < MT) {
        int rr = tid < rows ? tid : rows - 1;
        toks_s[tid] = list_tok[(size_t)e * N_TOK + base + rr];
        wts_s[tid] = list_w[(size_t)e * N_TOK + base + rr];
    }
    // stage x tile (fp32 -> bf16) into A-frag layout (1024 16B chunks)
    for (int c = tid; c < 1024; c += 256) {
        int row = c >> 4;
        int kchunk = c & 15;
        int rr = row < rows ? row : rows - 1;
        int tok = list_tok[(size_t)e * N_TOK + base + rr];
        const float4* src = (const float4*)(x + (size_t)tok * DIN + kchunk * 8);
        float4 lo = src[0], hi = src[1];
        u16x8 v;
        v[0] = f2bf(lo.x); v[1] = f2bf(lo.y); v[2] = f2bf(lo.z); v[3] = f2bf(lo.w);
        v[4] = f2bf(hi.x); v[5] = f2bf(hi.y); v[6] = f2bf(hi.z); v[7] = f2bf(hi.w);
        int kstep = kchunk >> 2, qq = kchunk & 3;
        int dchunk = (kstep * 4 + (row >> 4)) * 64 + qq * 16 + (row & 15);
        ((u16x8*)bufA)[dchunk] = v;
    }
    __syncthreads();

    const bf16x8* Albs = (const bf16x8*)bufA;
    const bf16x8* Hlbs = (const bf16x8*)bufH;

    // ---- GEMM1: x[64x128] @ W1[128x256] -> h1 ----
    f32x4 acc[4][4];
#pragma unroll
    for (int mt = 0; mt < 4; mt++)
#pragma unroll
        for (int nt = 0; nt < 4; nt++) acc[mt][nt] = (f32x4){0.f, 0.f, 0.f, 0.f};
    const bf16x8* B1 = (const bf16x8*)(wt1f + (size_t)e * 4096 * 8);
#pragma unroll
    for (int kstep = 0; kstep < 4; kstep++) {
        bf16x8 a[4];
#pragma unroll
        for (int mt = 0; mt < 4; mt++) a[mt] = Albs[(kstep * 4 + mt) * 64 + lane];
#pragma unroll
        for (int nt = 0; nt < 4; nt++) {
            bf16x8 b = B1[((w * 4 + nt) * 4 + kstep) * 64 + lane];
#pragma unroll
            for (int mt = 0; mt < 4; mt++)
                acc[mt][nt] = __builtin_amdgcn_mfma_f32_16x16x32_bf16(a[mt], b, acc[mt][nt], 0, 0, 0);
        }
    }
    // epilogue 1: bias + relu -> bufH (h1) in A-frag layout
#pragma unroll
    for (int nt = 0; nt < 4; nt++) {
        int nn = (w * 4 + nt) * 16 + mcol;
        float bias = b1[e * HD + nn];
        int kstep = nn >> 5, qq = (nn >> 3) & 3, jj = nn & 7;
#pragma unroll
        for (int mt = 0; mt < 4; mt++) {
#pragma unroll
            for (int r = 0; r < 4; r++) {
                float v = acc[mt][nt][r] + bias;
                v = v > 0.f ? v : 0.f;
                int chunk = (kstep * 4 + mt) * 64 + qq * 16 + q * 4 + r;
                bufH[chunk * 8 + jj] = f2bf(v);
            }
        }
    }
    __syncthreads();

    // ---- GEMM2: h1[64x256] @ W2[256x256] -> h2 (regs) ----
    f32x4 acc2[4][4];
#pragma unroll
    for (int mt = 0; mt < 4; mt++)
#pragma unroll
        for (int nt = 0; nt < 4; nt++) acc2[mt][nt] = (f32x4){0.f, 0.f, 0.f, 0.f};
    const bf16x8* B2 = (const bf16x8*)(wt2f + (size_t)e * 8192 * 8);
#pragma unroll
    for (int kstep = 0; kstep < 8; kstep++) {
        bf16x8 a[4];
#pragma unroll
        for (int mt = 0; mt < 4; mt++) a[mt] = Hlbs[(kstep * 4 + mt) * 64 + lane];
#pragma unroll
        for (int nt = 0; nt < 4; nt++) {
            bf16x8 b = B2[((w * 4 + nt) * 8 + kstep) * 64 + lane];
#pragma unroll
            for (int mt = 0; mt < 4; mt++)
                acc2[mt][nt] = __builtin_amdgcn_mfma_f32_16x16x32_bf16(a[mt], b, acc2[mt][nt], 0, 0, 0);
        }
    }
    __syncthreads();  // all waves done READING h1 before we overwrite bufH
    // epilogue 2: bias + relu -> bufH (h2 over h1; h1 is dead)
#pragma unroll
    for (int nt = 0; nt < 4; nt++) {
        int nn = (w * 4 + nt) * 16 + mcol;
        float bias = b2[e * HD + nn];
        int kstep = nn >> 5, qq = (nn >> 3) & 3, jj = nn & 7;
#pragma unroll
        for (int mt = 0; mt < 4; mt++) {
#pragma unroll
            for (int r = 0; r < 4; r++) {
                float v = acc2[mt][nt][r] + bias;
                v = v > 0.f ? v : 0.f;
                int chunk = (kstep * 4 + mt) * 64 + qq * 16 + q * 4 + r;
                bufH[chunk * 8 + jj] = f2bf(v);
            }
        }
    }
    __syncthreads();

    // ---- GEMM3: h2[64x256] @ Wo[256x128] -> y; weighted atomic combine ----
    f32x4 acc3[4][2];
#pragma unroll
    for (int mt = 0; mt < 4; mt++)
#pragma unroll
        for (int nt = 0; nt < 2; nt++) acc3[mt][nt] = (f32x4){0.f, 0.f, 0.f, 0.f};
    const bf16x8* B3 = (const bf16x8*)wotf;
#pragma unroll
    for (int kstep = 0; kstep < 8; kstep++) {
        bf16x8 a[4];
#pragma unroll
        for (int mt = 0; mt < 4; mt++) a[mt] = Hlbs[(kstep * 4 + mt) * 64 + lane];
#pragma unroll
        for (int nt = 0; nt < 2; nt++) {
            bf16x8 b = B3[((w * 2 + nt) * 8 + kstep) * 64 + lane];
#pragma unroll
            for (int mt = 0; mt < 4; mt++)
                acc3[mt][nt] = __builtin_amdgcn_mfma_f32_16x16x32_bf16(a[mt], b, acc3[mt][nt], 0, 0, 0);
        }
    }
#pragma unroll
    for (int mt = 0; mt < 4; mt++) {
#pragma unroll
        for (int r = 0; r < 4; r++) {
            int row = mt * 16 + q * 4 + r;
            if (row < rows) {
                int tok = toks_s[row];
                float wgt = wts_s[row];
                float* dst = out + (size_t)tok * DOUT;
#pragma unroll
                for (int nt = 0; nt < 2; nt++) {
                    int col = (w * 2 + nt) * 16 + mcol;
                    atomicAdd(&dst[col], wgt * acc3[mt][nt][r]);
                }
            }
        }
    }
}

extern "C" void kernel_launch(void* const* d_in, const int* in_sizes, int n_in,
                              void* d_out, int out_size, void* d_ws, size_t ws_size,
                              hipStream_t stream) {
    const float* x  = (const float*)d_in[0];
    const float* Wg = (const float*)d_in[1];
    const float* W1 = (const float*)d_in[2];
    const float* b1 = (const float*)d_in[3];
    const float* W2 = (const float*)d_in[4];
    const float* b2 = (const float*)d_in[5];
    const float* Wo = (const float*)d_in[6];
    const float* bo = (const float*)d_in[7];
    float* out = (float*)d_out;

    char* ws = (char*)d_ws;
    size_t off = 0;
    int* counts    = (int*)(ws + off);    off += 256;
    int* list_tok  = (int*)(ws + off);    off += (size_t)NEXP * N_TOK * 4;
    float* list_w  = (float*)(ws + off);  off += (size_t)NEXP * N_TOK * 4;
    ushort_t* wt1f = (ushort_t*)(ws + off); off += (size_t)NEXP * DIN * HD * 2;
    ushort_t* wt2f = (ushort_t*)(ws + off); off += (size_t)NEXP * HD * HD * 2;
    ushort_t* wotf = (ushort_t*)(ws + off); off += (size_t)HD * DOUT * 2;

    hipMemsetAsync(counts, 0, 256, stream);
    pack_weights<<<400, 256, 0, stream>>>(W1, W2, Wo, wt1f, wt2f, wotf);
    router_kernel<<<N_TOK / RT_TPB, RT_BLOCK, 0, stream>>>(x, Wg, counts, list_tok, list_w);
    init_out<<<(N_TOK * DOUT / 4) / 256, 256, 0, stream>>>(bo, out);
    expert_kernel<<<NEXP * MAX_TILES, 256, 0, stream>>>(x, counts, list_tok, list_w,
                                                        wt1f, wt2f, wotf, b1, b2, out);
}